// Round 4
// baseline (269.775 us; speedup 1.0000x reference)
//
#include <hip/hip_runtime.h>

#define N_NODES 50000
#define N_EDGES 800000
#define D_IN 96
#define HID 128
#define NB 391              // buckets of 128 nodes
#define BCAP 3072
#define AECAP 768           // per-block edge-index LDS cache (16 nodes, mean 256)

typedef __attribute__((ext_vector_type(8))) _Float16 halfx8;
typedef __attribute__((ext_vector_type(4))) _Float16 half4v;
typedef __attribute__((ext_vector_type(2))) _Float16 half2v;
typedef __attribute__((ext_vector_type(16))) float f32x16;

__device__ inline float dot2acc(half2v a, half2v b, float c) {
#if __has_builtin(__builtin_amdgcn_fdot2)
    return __builtin_amdgcn_fdot2(a, b, c, false);
#else
    return c + (float)a[0] * (float)b[0] + (float)a[1] * (float)b[1];
#endif
}

__device__ inline halfx8 relu8(halfx8 s) {
#if __has_builtin(__builtin_elementwise_max)
    return __builtin_elementwise_max(s, (halfx8)0);
#else
    halfx8 r;
#pragma unroll
    for (int i = 0; i < 8; i++) r[i] = s[i] > (_Float16)0 ? s[i] : (_Float16)0;
    return r;
#endif
}

// ---------------------------------------------------------------------------
// Merged: bucket histogram (blocks 0..195) + weight pack (blocks 196..500).
// Pack layout: W_in@0(12288), W1@12288, W2@28672, Wm1a@45056, Wm1b@61440,
// Wm2h@77824 (128).
// ---------------------------------------------------------------------------
__global__ __launch_bounds__(256) void hist_pack_kernel(const int* __restrict__ dst,
                                                        int* __restrict__ bhist,
                                                        const float* __restrict__ W_in,
                                                        const float* __restrict__ W1,
                                                        const float* __restrict__ W2,
                                                        const float* __restrict__ Wm1,
                                                        const float* __restrict__ Wm2,
                                                        _Float16* __restrict__ packed) {
    __shared__ int lh[NB];
    int t = threadIdx.x;
    if (blockIdx.x < 196) {
        for (int i = t; i < NB; i += 256) lh[i] = 0;
        __syncthreads();
        int base = blockIdx.x * 4096;
#pragma unroll
        for (int i = 0; i < 16; i++) {
            int e = base + i * 256 + t;
            if (e < N_EDGES) atomicAdd(&lh[dst[e] >> 7], 1);
        }
        __syncthreads();
        for (int i = t; i < NB; i += 256) atomicAdd(&bhist[i], lh[i]);
        return;
    }
    int g = (blockIdx.x - 196) * 256 + t;
    if (g >= 77952) return;
    if (g >= 77824) { packed[g] = (_Float16)Wm2[g - 77824]; return; }
    const float* Wsrc;
    int K, u;
    if (g < 12288)      { Wsrc = W_in;            K = 96;  u = g; }
    else if (g < 28672) { Wsrc = W1;              K = 128; u = g - 12288; }
    else if (g < 45056) { Wsrc = W2;              K = 128; u = g - 28672; }
    else if (g < 61440) { Wsrc = Wm1;             K = 128; u = g - 45056; }
    else                { Wsrc = Wm1 + 128 * 128; K = 128; u = g - 61440; }
    int steps = K >> 4;
    int cb = u / (steps * 512);
    int rem = u - cb * steps * 512;
    int s = rem >> 9;
    int lane = (rem >> 3) & 63;
    int j = rem & 7;
    int k = s * 16 + ((lane >> 5) << 3) + j;
    int n = (cb << 5) + (lane & 31);
    packed[g] = (_Float16)Wsrc[k * 128 + n];
}

__global__ __launch_bounds__(512) void scan_buckets_kernel(const int* __restrict__ bhist,
                                                           int* __restrict__ boff,
                                                           int* __restrict__ bcursor) {
    __shared__ int s[512];
    int t = threadIdx.x;
    int v = (t < NB) ? bhist[t] : 0;
    s[t] = v;
    __syncthreads();
    for (int off = 1; off < 512; off <<= 1) {
        int u = (t >= off) ? s[t - off] : 0;
        __syncthreads();
        s[t] += u;
        __syncthreads();
    }
    if (t < NB) {
        int ex = s[t] - v;
        boff[t] = ex;
        bcursor[t] = ex;
    }
    if (t == NB - 1) boff[NB] = s[t];
}

__global__ __launch_bounds__(512) void bin_kernel(const int* __restrict__ src,
                                                  const int* __restrict__ dst,
                                                  int* __restrict__ bcursor,
                                                  unsigned long long* __restrict__ binned) {
    __shared__ int lh[NB];
    __shared__ int gbs[NB];
    int t = threadIdx.x;
    for (int i = t; i < NB; i += 512) lh[i] = 0;
    __syncthreads();
    int base = blockIdx.x * 8192;
    unsigned long long pk[16];
    int bb[16], rk[16];
#pragma unroll
    for (int i = 0; i < 16; i++) {
        int e = base + i * 512 + t;
        bb[i] = -1;
        if (e < N_EDGES) {
            int s = src[e], d = dst[e];
            int b = d >> 7;
            bb[i] = b;
            pk[i] = ((unsigned long long)s << 27) |
                    ((unsigned long long)(d & 127) << 20) | (unsigned long long)e;
            rk[i] = atomicAdd(&lh[b], 1);
        }
    }
    __syncthreads();
    for (int i = t; i < NB; i += 512) gbs[i] = atomicAdd(&bcursor[i], lh[i]);
    __syncthreads();
#pragma unroll
    for (int i = 0; i < 16; i++) {
        if (bb[i] >= 0) binned[gbs[bb[i]] + rk[i]] = pk[i];
    }
}

// Bucket sort: per-thread payload kept in statically-indexed registers
// (LDS stash removed: 49KB -> 25KB LDS).
__global__ __launch_bounds__(256) void bucket_sort_kernel(const unsigned long long* __restrict__ binned,
                                                          const int* __restrict__ boff,
                                                          int* __restrict__ ce_src,
                                                          int* __restrict__ ce_eid,
                                                          int* __restrict__ ce_dst,
                                                          int* __restrict__ csr_ptr,
                                                          float* __restrict__ dinv) {
    __shared__ int2 sorted[BCAP];
    __shared__ int cntA[128], sc[128];
    int b = blockIdx.x;
    int t = threadIdx.x;
    int base = boff[b];
    int k = boff[b + 1] - base;
    if (k > BCAP) k = BCAP;
    if (t < 128) cntA[t] = 0;
    __syncthreads();
    unsigned long long pk[12];
    int rk[12];
#pragma unroll
    for (int m = 0; m < 12; m++) {
        int i = t + m * 256;
        rk[m] = -1;
        if (i < k) {
            unsigned long long p = binned[base + i];
            pk[m] = p;
            int d = (int)((p >> 20) & 127);
            rk[m] = atomicAdd(&cntA[d], 1);
        }
    }
    __syncthreads();
    if (t < 128) sc[t] = cntA[t];
    __syncthreads();
    for (int off = 1; off < 128; off <<= 1) {
        int u = 0;
        if (t < 128 && t >= off) u = sc[t - off];
        __syncthreads();
        if (t < 128) sc[t] += u;
        __syncthreads();
    }
#pragma unroll
    for (int m = 0; m < 12; m++) {
        if (rk[m] >= 0) {
            unsigned long long p = pk[m];
            int d = (int)((p >> 20) & 127);
            int pos = sc[d] - cntA[d] + rk[m];
            int srcn = (int)(p >> 27);
            int eid = (int)(p & 0xFFFFF);
            sorted[pos] = make_int2(srcn | (d << 16), eid);
        }
    }
    __syncthreads();
    for (int i = t; i < k; i += 256) {
        int2 se = sorted[i];
        ce_src[base + i] = se.x & 0xFFFF;
        ce_eid[base + i] = se.y;
        ce_dst[base + i] = (b << 7) + (se.x >> 16);
    }
    if (t < 128) {
        int node = (b << 7) + t;
        if (node < N_NODES) {
            csr_ptr[node] = base + sc[t] - cntA[t];
            dinv[node] = 1.0f / sqrtf((float)(cntA[t] + 1));
        }
    }
    if (b == NB - 1 && t == 0) csr_ptr[N_NODES] = boff[NB];
}

// ---------------------------------------------------------------------------
// Fused input: y1 = (relu(x@W_in + b_in) @ W1) * dinv[row]. h0 LDS-only.
// y1 written SLICE-MAJOR [4][N_NODES][32] (wave == slice).
// ---------------------------------------------------------------------------
__global__ __launch_bounds__(256) void fused_in_kernel(const float* __restrict__ x,
                                                       const _Float16* __restrict__ WpIn,
                                                       const _Float16* __restrict__ Wp1,
                                                       const float* __restrict__ b_in,
                                                       const float* __restrict__ dinv,
                                                       _Float16* __restrict__ y1, int M) {
    __shared__ _Float16 As[32 * 104];
    __shared__ _Float16 Hs[32 * 136];
    int tid = threadIdx.x;
    int M0 = blockIdx.x * 32;
    for (int i = tid; i < 32 * 24; i += 256) {
        int r = i / 24, c = i - r * 24;
        float4 v = make_float4(0.f, 0.f, 0.f, 0.f);
        int row = M0 + r;
        if (row < M) v = *(const float4*)&x[(size_t)row * 96 + c * 4];
        half2v a = {(_Float16)v.x, (_Float16)v.y};
        half2v b = {(_Float16)v.z, (_Float16)v.w};
        *(half2v*)&As[r * 104 + c * 4] = a;
        *(half2v*)&As[r * 104 + c * 4 + 2] = b;
    }
    __syncthreads();

    int wave = tid >> 6, lane = tid & 63;
    int col = wave * 32 + (lane & 31);
    {
        const halfx8* bp = (const halfx8*)WpIn + (size_t)wave * 6 * 64 + lane;
        const _Float16* arow = &As[(lane & 31) * 104 + ((lane >> 5) << 3)];
        f32x16 acc = {};
#pragma unroll
        for (int s = 0; s < 6; s++) {
            halfx8 a = *(const halfx8*)&arow[s * 16];
            acc = __builtin_amdgcn_mfma_f32_32x32x16_f16(a, bp[s * 64], acc, 0, 0, 0);
        }
        float bA = b_in[col];
#pragma unroll
        for (int r = 0; r < 16; r++) {
            int rl = (r & 3) + 8 * (r >> 2) + 4 * (lane >> 5);
            Hs[rl * 136 + col] = (_Float16)fmaxf(acc[r] + bA, 0.f);
        }
    }
    __syncthreads();
    {
        const halfx8* bp = (const halfx8*)Wp1 + (size_t)wave * 8 * 64 + lane;
        const _Float16* arow = &Hs[(lane & 31) * 136 + ((lane >> 5) << 3)];
        f32x16 acc = {};
#pragma unroll
        for (int s = 0; s < 8; s++) {
            halfx8 a = *(const halfx8*)&arow[s * 16];
            acc = __builtin_amdgcn_mfma_f32_32x32x16_f16(a, bp[s * 64], acc, 0, 0, 0);
        }
#pragma unroll
        for (int r = 0; r < 16; r++) {
            int rl = (r & 3) + 8 * (r >> 2) + 4 * (lane >> 5);
            int grow = M0 + rl;
            if (grow < M) {
                y1[((size_t)wave * N_NODES + grow) * 32 + (lane & 31)] =
                    (_Float16)(acc[r] * dinv[grow]);
            }
        }
    }
}

// ---------------------------------------------------------------------------
// fp16 MFMA node GEMM, M=32 tile, wave = col-tile. K=128 only.
// A read SLICE-MAJOR [4][N_NODES][32]; out written SLICE-MAJOR.
// (LDS image identical: (c>>2)*32+(c&3)*8 == c*8.)
// ---------------------------------------------------------------------------
__global__ __launch_bounds__(256) void gemm_f16_kernel(const _Float16* __restrict__ A,
                                                       const _Float16* __restrict__ Wp,
                                                       const float* __restrict__ bias,
                                                       const float* __restrict__ rowscale,
                                                       _Float16* __restrict__ out,
                                                       int M, int steps, int dorelu) {
    const int K = 128;
    __shared__ _Float16 As[32 * 136];
    int tid = threadIdx.x;
    int M0 = blockIdx.x * 32;
    int stride = K + 8;
    for (int i = tid; i < 32 * 16; i += 256) {
        int r = i >> 4, c = i & 15;
        uint4 v = make_uint4(0, 0, 0, 0);
        int row = M0 + r;
        if (row < M)
            v = *(const uint4*)&A[((size_t)(c >> 2) * N_NODES + row) * 32 + (c & 3) * 8];
        *(uint4*)&As[r * stride + c * 8] = v;
    }
    __syncthreads();

    int wave = tid >> 6, lane = tid & 63;
    const halfx8* bp = (const halfx8*)Wp + (size_t)wave * steps * 64 + lane;
    const _Float16* arow = &As[(lane & 31) * stride + ((lane >> 5) << 3)];
    f32x16 acc = {};
    for (int s = 0; s < steps; s++) {
        halfx8 a = *(const halfx8*)&arow[s * 16];
        acc = __builtin_amdgcn_mfma_f32_32x32x16_f16(a, bp[s * 64], acc, 0, 0, 0);
    }
    int col = wave * 32 + (lane & 31);
    float bA = bias ? bias[col] : 0.f;
#pragma unroll
    for (int r = 0; r < 16; r++) {
        int rl = (r & 3) + 8 * (r >> 2) + 4 * (lane >> 5);
        int grow = M0 + rl;
        if (grow < M) {
            float sc = rowscale ? rowscale[grow] : 1.f;
            float v0 = (acc[r] + bA) * sc;
            if (dorelu) v0 = fmaxf(v0, 0.f);
            out[((size_t)wave * N_NODES + grow) * 32 + (lane & 31)] = (_Float16)v0;
        }
    }
}

// Dual-output GEMM: U = A@WpU + bm1, V = A@WpV (A staged once). M=32 tile.
// A read SLICE-MAJOR; U/V written NODE-MAJOR (edge_mlp gathers 256B rows).
__global__ __launch_bounds__(256) void gemm_uv_kernel(const _Float16* __restrict__ A,
                                                      const _Float16* __restrict__ WpU,
                                                      const _Float16* __restrict__ WpV,
                                                      const float* __restrict__ bm1,
                                                      _Float16* __restrict__ U,
                                                      _Float16* __restrict__ V,
                                                      int M) {
    const int K = 128, steps = 8;
    __shared__ _Float16 As[32 * 136];
    int tid = threadIdx.x;
    int M0 = blockIdx.x * 32;
    int stride = K + 8;
    for (int i = tid; i < 32 * 16; i += 256) {
        int r = i >> 4, c = i & 15;
        uint4 v = make_uint4(0, 0, 0, 0);
        int row = M0 + r;
        if (row < M)
            v = *(const uint4*)&A[((size_t)(c >> 2) * N_NODES + row) * 32 + (c & 3) * 8];
        *(uint4*)&As[r * stride + c * 8] = v;
    }
    __syncthreads();

    int wave = tid >> 6, lane = tid & 63;
    const halfx8* bu = (const halfx8*)WpU + (size_t)wave * steps * 64 + lane;
    const halfx8* bv = (const halfx8*)WpV + (size_t)wave * steps * 64 + lane;
    const _Float16* arow = &As[(lane & 31) * stride + ((lane >> 5) << 3)];
    f32x16 au = {}, av = {};
#pragma unroll
    for (int s = 0; s < steps; s++) {
        halfx8 a = *(const halfx8*)&arow[s * 16];
        au = __builtin_amdgcn_mfma_f32_32x32x16_f16(a, bu[s * 64], au, 0, 0, 0);
        av = __builtin_amdgcn_mfma_f32_32x32x16_f16(a, bv[s * 64], av, 0, 0, 0);
    }
    int col = wave * 32 + (lane & 31);
    float bA = bm1[col];
#pragma unroll
    for (int r = 0; r < 16; r++) {
        int rl = (r & 3) + 8 * (r >> 2) + 4 * (lane >> 5);
        int grow = M0 + rl;
        if (grow < M) {
            U[(size_t)grow * 128 + col] = (_Float16)(au[r] + bA);
            V[(size_t)grow * 128 + col] = (_Float16)av[r];
        }
    }
}

// ---------------------------------------------------------------------------
// GCN aggregation, slice-major + XCD-pinned. R0-R3 lesson: traffic-bound at
// the blended L2/L3 random-gather ceiling (~6 TB/s); MLP changes neutral.
// Fix: y stored [4][N][32] so slice s is a CONTIGUOUS 3.2MB table that fits
// one XCD's 4MiB L2 (R1's node-major slicing kept 6.4MB line-working-set +
// 2x line over-fetch -> failed). blockIdx%8 pins slice s to XCDs {2s,2s+1};
// mean row reuse 16x then served from L2. Gather = 16 lanes x 4B = 64B.
// DO NOT fuse into GEMM (R7 lesson: grid collapse kills gather parallelism).
// ---------------------------------------------------------------------------
__global__ __launch_bounds__(256, 6) void aggregate_kernel(const _Float16* __restrict__ y,
                                                           const float* __restrict__ dinv,
                                                           const int* __restrict__ ptr,
                                                           const int* __restrict__ ce_src,
                                                           const float* __restrict__ bias,
                                                           _Float16* __restrict__ out) {
    __shared__ int sidx[AECAP];
    __shared__ int sptr[17];
    int b = blockIdx.x;
    int sl = (b & 7) >> 1;                     // slice 0..3 -> XCD pair
    int o = ((b >> 3) << 1) + (b & 1);         // node-group ordinal
    if (o >= 3125) return;                     // 3125 * 16 = 50000
    int node0 = o * 16;
    int tid = threadIdx.x;
    if (tid < 17) sptr[tid] = ptr[node0 + tid];
    __syncthreads();
    int base = sptr[0];
    int tot = sptr[16] - base;
    bool fit = (tot <= AECAP);
    if (fit) {
        for (int i = tid; i < tot; i += 256) sidx[i] = ce_src[base + i];
    }
    __syncthreads();

    int g = tid >> 4;                          // 16 node-groups
    int l = tid & 15;                          // 16 lanes x 4B = 64B row-slice
    int node = node0 + g;
    float di = dinv[node];
    const _Float16* ys = y + (size_t)sl * N_NODES * 32 + l * 2;
    half2v self = *(const half2v*)&ys[(size_t)node * 32];
    float a0 = (float)self[0], a1 = (float)self[1];
    float b0 = 0.f, b1 = 0.f;
    int s0 = sptr[g], s1 = sptr[g + 1];

    if (fit) {
        int j = s0 - base, e = s1 - base;
        while (j < e) {
            half2v v[16];
#pragma unroll
            for (int k = 0; k < 16; k++) {
                int idx = j + k;
                int n = sidx[idx < e ? idx : e - 1];
                v[k] = *(const half2v*)&ys[(size_t)n * 32];
            }
            __builtin_amdgcn_sched_barrier(0);   // keep all 16 gathers in flight
#pragma unroll
            for (int k = 0; k < 16; k += 2) {
                float m0 = (j + k < e) ? 1.f : 0.f;
                float m1 = (j + k + 1 < e) ? 1.f : 0.f;
                a0 += m0 * (float)v[k][0];     a1 += m0 * (float)v[k][1];
                b0 += m1 * (float)v[k + 1][0]; b1 += m1 * (float)v[k + 1][1];
            }
            j += 16;
        }
    } else {
        // cap-overflow fallback (P ~ 0 for Poisson(256) > 768, kept for safety)
        for (int j = s0; j < s1; j++) {
            int n = ce_src[j];
            half2v v = *(const half2v*)&ys[(size_t)n * 32];
            a0 += (float)v[0]; a1 += (float)v[1];
        }
    }
    float2 bv = *(const float2*)&bias[sl * 32 + l * 2];
    half2v ov;
    ov[0] = (_Float16)fmaxf(di * (a0 + b0) + bv.x, 0.f);
    ov[1] = (_Float16)fmaxf(di * (a1 + b1) + bv.y, 0.f);
    *(half2v*)&out[((size_t)sl * N_NODES + node) * 32 + l * 2] = ov;
}

// ---------------------------------------------------------------------------
// Edge MLP: 128 edges/block, 8 edges per 16-lane group (16 gathers in
// flight/thread — pinned with sched_barrier), packed fp16 add+relu +
// v_dot2_f32_f16 accumulation.
// ---------------------------------------------------------------------------
__global__ __launch_bounds__(256) void edge_mlp_kernel(const _Float16* __restrict__ Ub,
                                                       const _Float16* __restrict__ Vb,
                                                       const int* __restrict__ ce_src,
                                                       const int* __restrict__ ce_eid,
                                                       const int* __restrict__ ce_dst,
                                                       const _Float16* __restrict__ Wm2h,
                                                       const float* __restrict__ bm2,
                                                       float* __restrict__ out) {
    __shared__ int ssrc[128], sdst[128], seid[128];
    int tid = threadIdx.x;
    int e0 = blockIdx.x * 128;
    if (tid < 128) {
        ssrc[tid] = ce_src[e0 + tid];
        seid[tid] = ce_eid[e0 + tid];
    } else {
        sdst[tid - 128] = ce_dst[e0 + tid - 128];
    }
    __syncthreads();
    int g = tid >> 4;     // group 0..15
    int l = tid & 15;     // cols l*8 .. l*8+7
    halfx8 wv = *(const halfx8*)&Wm2h[l * 8];
    half2v w0 = {wv[0], wv[1]}, w1 = {wv[2], wv[3]}, w2 = {wv[4], wv[5]}, w3 = {wv[6], wv[7]};
    halfx8 uu[8], vv[8];
#pragma unroll
    for (int k = 0; k < 8; k++) {
        int e = g + 16 * k;
        uu[k] = *(const halfx8*)&Ub[(size_t)ssrc[e] * 128 + l * 8];
        vv[k] = *(const halfx8*)&Vb[(size_t)sdst[e] * 128 + l * 8];
    }
    __builtin_amdgcn_sched_barrier(0);   // keep all 16 gathers in flight
    float p[8];
#pragma unroll
    for (int k = 0; k < 8; k++) {
        halfx8 s = relu8(uu[k] + vv[k]);
        half2v s0 = {s[0], s[1]}, s1 = {s[2], s[3]}, s2 = {s[4], s[5]}, s3 = {s[6], s[7]};
        float acc = dot2acc(s0, w0, 0.f);
        acc = dot2acc(s1, w1, acc);
        acc = dot2acc(s2, w2, acc);
        p[k] = dot2acc(s3, w3, acc);
    }
#pragma unroll
    for (int d = 1; d < 16; d <<= 1) {
#pragma unroll
        for (int k = 0; k < 8; k++) p[k] += __shfl_xor(p[k], d);
    }
    if (l == 0) {
        float bb = bm2[0];
#pragma unroll
        for (int k = 0; k < 8; k++) out[seid[g + 16 * k]] = p[k] + bb;
    }
}

// ---------------------------------------------------------------------------
extern "C" void kernel_launch(void* const* d_in, const int* in_sizes, int n_in,
                              void* d_out, int out_size, void* d_ws, size_t ws_size,
                              hipStream_t stream) {
    const float* x    = (const float*)d_in[0];
    const int* eidx   = (const int*)d_in[1];
    const float* W_in = (const float*)d_in[2];
    const float* b_in = (const float*)d_in[3];
    const float* W1   = (const float*)d_in[4];
    const float* b1   = (const float*)d_in[5];
    const float* W2   = (const float*)d_in[6];
    const float* b2   = (const float*)d_in[7];
    const float* Wm1  = (const float*)d_in[8];
    const float* bm1  = (const float*)d_in[9];
    const float* Wm2  = (const float*)d_in[10];
    const float* bm2  = (const float*)d_in[11];
    float* out = (float*)d_out;
    const int* src = eidx;
    const int* dst = eidx + N_EDGES;

    char* w = (char*)d_ws;
    size_t off = 0;
    auto alloc = [&](size_t bytes) -> char* {
        char* p = w + off;
        off = (off + bytes + 255) & ~(size_t)255;
        return p;
    };
    int* bhist    = (int*)alloc((size_t)NB * 4);
    int* boff     = (int*)alloc((size_t)(NB + 1) * 4);
    int* bcursor  = (int*)alloc((size_t)NB * 4);
    int* csr_ptr  = (int*)alloc((size_t)(N_NODES + 1) * 4);
    float* dinv   = (float*)alloc((size_t)N_NODES * 4);
    unsigned long long* binned = (unsigned long long*)alloc((size_t)N_EDGES * 8);
    int* ce_src   = (int*)alloc((size_t)N_EDGES * 4);
    int* ce_eid   = (int*)alloc((size_t)N_EDGES * 4);
    int* ce_dst   = (int*)alloc((size_t)N_EDGES * 4);
    _Float16* Wp  = (_Float16*)alloc((size_t)77952 * 2);
    _Float16* y1  = (_Float16*)alloc((size_t)N_NODES * HID * 2);
    _Float16* y2  = (_Float16*)alloc((size_t)N_NODES * HID * 2);
    _Float16* hbuf = (_Float16*)alloc((size_t)N_NODES * HID * 2);
    _Float16* Ub  = (_Float16*)alloc((size_t)N_NODES * HID * 2);
    _Float16* Vb  = (_Float16*)alloc((size_t)N_NODES * HID * 2);

    const _Float16* WpIn  = Wp;              // K=96, steps 6
    const _Float16* Wp1   = Wp + 12288;      // K=128
    const _Float16* Wp2   = Wp + 28672;
    const _Float16* WpM1a = Wp + 45056;
    const _Float16* WpM1b = Wp + 61440;
    const _Float16* Wm2h  = Wp + 77824;

    // CSR build (counting sort) + weight pack (merged into pass 1)
    hipMemsetAsync(bhist, 0, (size_t)NB * 4, stream);
    hist_pack_kernel<<<196 + 305, 256, 0, stream>>>(dst, bhist, W_in, W1, W2, Wm1, Wm2, Wp);
    scan_buckets_kernel<<<1, 512, 0, stream>>>(bhist, boff, bcursor);
    bin_kernel<<<98, 512, 0, stream>>>(src, dst, bcursor, binned);
    bucket_sort_kernel<<<NB, 256, 0, stream>>>(binned, boff, ce_src, ce_eid, ce_dst,
                                               csr_ptr, dinv);

    int gblocks = (N_NODES + 31) / 32;  // 1563
    int ablocks = 1563 * 8;             // 4 slices x 3125 node-groups, XCD-interleaved
    // y1 = (relu(x@W_in+b_in) @ W1) * dinv          (slice-major)
    fused_in_kernel<<<gblocks, 256, 0, stream>>>(x, WpIn, Wp1, b_in, dinv, y1, N_NODES);
    // h1 = relu(dinv*(y1_self + sum y1[src]) + b1)  -> hbuf (slice-major)
    aggregate_kernel<<<ablocks, 256, 0, stream>>>(y1, dinv, csr_ptr, ce_src, b1, hbuf);
    // y2 = (h1 @ W2) * dinv                         -> y2 (slice-major)
    gemm_f16_kernel<<<gblocks, 256, 0, stream>>>(hbuf, Wp2, nullptr, dinv, y2,
                                                 N_NODES, 8, 0);
    // h2 = relu(dinv*(y2_self + sum y2[src]) + b2)  -> hbuf (slice-major)
    aggregate_kernel<<<ablocks, 256, 0, stream>>>(y2, dinv, csr_ptr, ce_src, b2, hbuf);
    // U = h2@Wm1a+bm1, V = h2@Wm1b                  -> Ub, Vb (node-major)
    gemm_uv_kernel<<<gblocks, 256, 0, stream>>>(hbuf, WpM1a, WpM1b, bm1, Ub, Vb, N_NODES);
    // logits (CSR order, scatter by original edge id)
    edge_mlp_kernel<<<N_EDGES / 128, 256, 0, stream>>>(Ub, Vb, ce_src, ce_eid, ce_dst,
                                                       Wm2h, bm2, out);
}

// Round 5
// 238.287 us; speedup vs baseline: 1.1321x; 1.1321x over previous
//
#include <hip/hip_runtime.h>

#define N_NODES 50000
#define N_EDGES 800000
#define D_IN 96
#define HID 128
#define NB 391              // buckets of 128 nodes
#define BCAP 3072
#define AECAP 1408          // per-block edge cache (64 nodes, mean 1024, +12 sigma)

typedef __attribute__((ext_vector_type(8))) _Float16 halfx8;
typedef __attribute__((ext_vector_type(4))) _Float16 half4v;
typedef __attribute__((ext_vector_type(2))) _Float16 half2v;
typedef __attribute__((ext_vector_type(16))) float f32x16;

__device__ inline float dot2acc(half2v a, half2v b, float c) {
#if __has_builtin(__builtin_amdgcn_fdot2)
    return __builtin_amdgcn_fdot2(a, b, c, false);
#else
    return c + (float)a[0] * (float)b[0] + (float)a[1] * (float)b[1];
#endif
}

__device__ inline halfx8 relu8(halfx8 s) {
#if __has_builtin(__builtin_elementwise_max)
    return __builtin_elementwise_max(s, (halfx8)0);
#else
    halfx8 r;
#pragma unroll
    for (int i = 0; i < 8; i++) r[i] = s[i] > (_Float16)0 ? s[i] : (_Float16)0;
    return r;
#endif
}

// ---------------------------------------------------------------------------
// Merged: bucket histogram (blocks 0..195) + weight pack (blocks 196..500).
// Pack layout: W_in@0(12288), W1@12288, W2@28672, Wm1a@45056, Wm1b@61440,
// Wm2h@77824 (128).
// ---------------------------------------------------------------------------
__global__ __launch_bounds__(256) void hist_pack_kernel(const int* __restrict__ dst,
                                                        int* __restrict__ bhist,
                                                        const float* __restrict__ W_in,
                                                        const float* __restrict__ W1,
                                                        const float* __restrict__ W2,
                                                        const float* __restrict__ Wm1,
                                                        const float* __restrict__ Wm2,
                                                        _Float16* __restrict__ packed) {
    __shared__ int lh[NB];
    int t = threadIdx.x;
    if (blockIdx.x < 196) {
        for (int i = t; i < NB; i += 256) lh[i] = 0;
        __syncthreads();
        int base = blockIdx.x * 4096;
#pragma unroll
        for (int i = 0; i < 16; i++) {
            int e = base + i * 256 + t;
            if (e < N_EDGES) atomicAdd(&lh[dst[e] >> 7], 1);
        }
        __syncthreads();
        for (int i = t; i < NB; i += 256) atomicAdd(&bhist[i], lh[i]);
        return;
    }
    int g = (blockIdx.x - 196) * 256 + t;
    if (g >= 77952) return;
    if (g >= 77824) { packed[g] = (_Float16)Wm2[g - 77824]; return; }
    const float* Wsrc;
    int K, u;
    if (g < 12288)      { Wsrc = W_in;            K = 96;  u = g; }
    else if (g < 28672) { Wsrc = W1;              K = 128; u = g - 12288; }
    else if (g < 45056) { Wsrc = W2;              K = 128; u = g - 28672; }
    else if (g < 61440) { Wsrc = Wm1;             K = 128; u = g - 45056; }
    else                { Wsrc = Wm1 + 128 * 128; K = 128; u = g - 61440; }
    int steps = K >> 4;
    int cb = u / (steps * 512);
    int rem = u - cb * steps * 512;
    int s = rem >> 9;
    int lane = (rem >> 3) & 63;
    int j = rem & 7;
    int k = s * 16 + ((lane >> 5) << 3) + j;
    int n = (cb << 5) + (lane & 31);
    packed[g] = (_Float16)Wsrc[k * 128 + n];
}

__global__ __launch_bounds__(512) void scan_buckets_kernel(const int* __restrict__ bhist,
                                                           int* __restrict__ boff,
                                                           int* __restrict__ bcursor) {
    __shared__ int s[512];
    int t = threadIdx.x;
    int v = (t < NB) ? bhist[t] : 0;
    s[t] = v;
    __syncthreads();
    for (int off = 1; off < 512; off <<= 1) {
        int u = (t >= off) ? s[t - off] : 0;
        __syncthreads();
        s[t] += u;
        __syncthreads();
    }
    if (t < NB) {
        int ex = s[t] - v;
        boff[t] = ex;
        bcursor[t] = ex;
    }
    if (t == NB - 1) boff[NB] = s[t];
}

__global__ __launch_bounds__(512) void bin_kernel(const int* __restrict__ src,
                                                  const int* __restrict__ dst,
                                                  int* __restrict__ bcursor,
                                                  unsigned long long* __restrict__ binned) {
    __shared__ int lh[NB];
    __shared__ int gbs[NB];
    int t = threadIdx.x;
    for (int i = t; i < NB; i += 512) lh[i] = 0;
    __syncthreads();
    int base = blockIdx.x * 8192;
    unsigned long long pk[16];
    int bb[16], rk[16];
#pragma unroll
    for (int i = 0; i < 16; i++) {
        int e = base + i * 512 + t;
        bb[i] = -1;
        if (e < N_EDGES) {
            int s = src[e], d = dst[e];
            int b = d >> 7;
            bb[i] = b;
            pk[i] = ((unsigned long long)s << 27) |
                    ((unsigned long long)(d & 127) << 20) | (unsigned long long)e;
            rk[i] = atomicAdd(&lh[b], 1);
        }
    }
    __syncthreads();
    for (int i = t; i < NB; i += 512) gbs[i] = atomicAdd(&bcursor[i], lh[i]);
    __syncthreads();
#pragma unroll
    for (int i = 0; i < 16; i++) {
        if (bb[i] >= 0) binned[gbs[bb[i]] + rk[i]] = pk[i];
    }
}

// Bucket sort: per-thread payload kept in statically-indexed registers
// (LDS stash removed: 49KB -> 25KB LDS).
__global__ __launch_bounds__(256) void bucket_sort_kernel(const unsigned long long* __restrict__ binned,
                                                          const int* __restrict__ boff,
                                                          int* __restrict__ ce_src,
                                                          int* __restrict__ ce_eid,
                                                          int* __restrict__ ce_dst,
                                                          int* __restrict__ csr_ptr,
                                                          float* __restrict__ dinv) {
    __shared__ int2 sorted[BCAP];
    __shared__ int cntA[128], sc[128];
    int b = blockIdx.x;
    int t = threadIdx.x;
    int base = boff[b];
    int k = boff[b + 1] - base;
    if (k > BCAP) k = BCAP;
    if (t < 128) cntA[t] = 0;
    __syncthreads();
    unsigned long long pk[12];
    int rk[12];
#pragma unroll
    for (int m = 0; m < 12; m++) {
        int i = t + m * 256;
        rk[m] = -1;
        if (i < k) {
            unsigned long long p = binned[base + i];
            pk[m] = p;
            int d = (int)((p >> 20) & 127);
            rk[m] = atomicAdd(&cntA[d], 1);
        }
    }
    __syncthreads();
    if (t < 128) sc[t] = cntA[t];
    __syncthreads();
    for (int off = 1; off < 128; off <<= 1) {
        int u = 0;
        if (t < 128 && t >= off) u = sc[t - off];
        __syncthreads();
        if (t < 128) sc[t] += u;
        __syncthreads();
    }
#pragma unroll
    for (int m = 0; m < 12; m++) {
        if (rk[m] >= 0) {
            unsigned long long p = pk[m];
            int d = (int)((p >> 20) & 127);
            int pos = sc[d] - cntA[d] + rk[m];
            int srcn = (int)(p >> 27);
            int eid = (int)(p & 0xFFFFF);
            sorted[pos] = make_int2(srcn | (d << 16), eid);
        }
    }
    __syncthreads();
    for (int i = t; i < k; i += 256) {
        int2 se = sorted[i];
        ce_src[base + i] = se.x & 0xFFFF;
        ce_eid[base + i] = se.y;
        ce_dst[base + i] = (b << 7) + (se.x >> 16);
    }
    if (t < 128) {
        int node = (b << 7) + t;
        if (node < N_NODES) {
            csr_ptr[node] = base + sc[t] - cntA[t];
            dinv[node] = 1.0f / sqrtf((float)(cntA[t] + 1));
        }
    }
    if (b == NB - 1 && t == 0) csr_ptr[N_NODES] = boff[NB];
}

// ---------------------------------------------------------------------------
// Fused input: y1 = (relu(x@W_in + b_in) @ W1) * dinv[row]. h0 LDS-only.
// y1 written SLICE-MAJOR [4][N_NODES][32] (wave == slice).
// ---------------------------------------------------------------------------
__global__ __launch_bounds__(256) void fused_in_kernel(const float* __restrict__ x,
                                                       const _Float16* __restrict__ WpIn,
                                                       const _Float16* __restrict__ Wp1,
                                                       const float* __restrict__ b_in,
                                                       const float* __restrict__ dinv,
                                                       _Float16* __restrict__ y1, int M) {
    __shared__ _Float16 As[32 * 104];
    __shared__ _Float16 Hs[32 * 136];
    int tid = threadIdx.x;
    int M0 = blockIdx.x * 32;
    for (int i = tid; i < 32 * 24; i += 256) {
        int r = i / 24, c = i - r * 24;
        float4 v = make_float4(0.f, 0.f, 0.f, 0.f);
        int row = M0 + r;
        if (row < M) v = *(const float4*)&x[(size_t)row * 96 + c * 4];
        half2v a = {(_Float16)v.x, (_Float16)v.y};
        half2v b = {(_Float16)v.z, (_Float16)v.w};
        *(half2v*)&As[r * 104 + c * 4] = a;
        *(half2v*)&As[r * 104 + c * 4 + 2] = b;
    }
    __syncthreads();

    int wave = tid >> 6, lane = tid & 63;
    int col = wave * 32 + (lane & 31);
    {
        const halfx8* bp = (const halfx8*)WpIn + (size_t)wave * 6 * 64 + lane;
        const _Float16* arow = &As[(lane & 31) * 104 + ((lane >> 5) << 3)];
        f32x16 acc = {};
#pragma unroll
        for (int s = 0; s < 6; s++) {
            halfx8 a = *(const halfx8*)&arow[s * 16];
            acc = __builtin_amdgcn_mfma_f32_32x32x16_f16(a, bp[s * 64], acc, 0, 0, 0);
        }
        float bA = b_in[col];
#pragma unroll
        for (int r = 0; r < 16; r++) {
            int rl = (r & 3) + 8 * (r >> 2) + 4 * (lane >> 5);
            Hs[rl * 136 + col] = (_Float16)fmaxf(acc[r] + bA, 0.f);
        }
    }
    __syncthreads();
    {
        const halfx8* bp = (const halfx8*)Wp1 + (size_t)wave * 8 * 64 + lane;
        const _Float16* arow = &Hs[(lane & 31) * 136 + ((lane >> 5) << 3)];
        f32x16 acc = {};
#pragma unroll
        for (int s = 0; s < 8; s++) {
            halfx8 a = *(const halfx8*)&arow[s * 16];
            acc = __builtin_amdgcn_mfma_f32_32x32x16_f16(a, bp[s * 64], acc, 0, 0, 0);
        }
#pragma unroll
        for (int r = 0; r < 16; r++) {
            int rl = (r & 3) + 8 * (r >> 2) + 4 * (lane >> 5);
            int grow = M0 + rl;
            if (grow < M) {
                y1[((size_t)wave * N_NODES + grow) * 32 + (lane & 31)] =
                    (_Float16)(acc[r] * dinv[grow]);
            }
        }
    }
}

// ---------------------------------------------------------------------------
// fp16 MFMA node GEMM, M=32 tile, wave = col-tile. K=128 only.
// A read SLICE-MAJOR [4][N_NODES][32]; out written SLICE-MAJOR.
// (LDS image identical: (c>>2)*32+(c&3)*8 == c*8.)
// ---------------------------------------------------------------------------
__global__ __launch_bounds__(256) void gemm_f16_kernel(const _Float16* __restrict__ A,
                                                       const _Float16* __restrict__ Wp,
                                                       const float* __restrict__ bias,
                                                       const float* __restrict__ rowscale,
                                                       _Float16* __restrict__ out,
                                                       int M, int steps, int dorelu) {
    const int K = 128;
    __shared__ _Float16 As[32 * 136];
    int tid = threadIdx.x;
    int M0 = blockIdx.x * 32;
    int stride = K + 8;
    for (int i = tid; i < 32 * 16; i += 256) {
        int r = i >> 4, c = i & 15;
        uint4 v = make_uint4(0, 0, 0, 0);
        int row = M0 + r;
        if (row < M)
            v = *(const uint4*)&A[((size_t)(c >> 2) * N_NODES + row) * 32 + (c & 3) * 8];
        *(uint4*)&As[r * stride + c * 8] = v;
    }
    __syncthreads();

    int wave = tid >> 6, lane = tid & 63;
    const halfx8* bp = (const halfx8*)Wp + (size_t)wave * steps * 64 + lane;
    const _Float16* arow = &As[(lane & 31) * stride + ((lane >> 5) << 3)];
    f32x16 acc = {};
    for (int s = 0; s < steps; s++) {
        halfx8 a = *(const halfx8*)&arow[s * 16];
        acc = __builtin_amdgcn_mfma_f32_32x32x16_f16(a, bp[s * 64], acc, 0, 0, 0);
    }
    int col = wave * 32 + (lane & 31);
    float bA = bias ? bias[col] : 0.f;
#pragma unroll
    for (int r = 0; r < 16; r++) {
        int rl = (r & 3) + 8 * (r >> 2) + 4 * (lane >> 5);
        int grow = M0 + rl;
        if (grow < M) {
            float sc = rowscale ? rowscale[grow] : 1.f;
            float v0 = (acc[r] + bA) * sc;
            if (dorelu) v0 = fmaxf(v0, 0.f);
            out[((size_t)wave * N_NODES + grow) * 32 + (lane & 31)] = (_Float16)v0;
        }
    }
}

// Dual-output GEMM: U = A@WpU + bm1, V = A@WpV (A staged once). M=32 tile.
// A read SLICE-MAJOR; U/V written NODE-MAJOR (edge_mlp gathers 256B rows).
__global__ __launch_bounds__(256) void gemm_uv_kernel(const _Float16* __restrict__ A,
                                                      const _Float16* __restrict__ WpU,
                                                      const _Float16* __restrict__ WpV,
                                                      const float* __restrict__ bm1,
                                                      _Float16* __restrict__ U,
                                                      _Float16* __restrict__ V,
                                                      int M) {
    const int K = 128, steps = 8;
    __shared__ _Float16 As[32 * 136];
    int tid = threadIdx.x;
    int M0 = blockIdx.x * 32;
    int stride = K + 8;
    for (int i = tid; i < 32 * 16; i += 256) {
        int r = i >> 4, c = i & 15;
        uint4 v = make_uint4(0, 0, 0, 0);
        int row = M0 + r;
        if (row < M)
            v = *(const uint4*)&A[((size_t)(c >> 2) * N_NODES + row) * 32 + (c & 3) * 8];
        *(uint4*)&As[r * stride + c * 8] = v;
    }
    __syncthreads();

    int wave = tid >> 6, lane = tid & 63;
    const halfx8* bu = (const halfx8*)WpU + (size_t)wave * steps * 64 + lane;
    const halfx8* bv = (const halfx8*)WpV + (size_t)wave * steps * 64 + lane;
    const _Float16* arow = &As[(lane & 31) * stride + ((lane >> 5) << 3)];
    f32x16 au = {}, av = {};
#pragma unroll
    for (int s = 0; s < steps; s++) {
        halfx8 a = *(const halfx8*)&arow[s * 16];
        au = __builtin_amdgcn_mfma_f32_32x32x16_f16(a, bu[s * 64], au, 0, 0, 0);
        av = __builtin_amdgcn_mfma_f32_32x32x16_f16(a, bv[s * 64], av, 0, 0, 0);
    }
    int col = wave * 32 + (lane & 31);
    float bA = bm1[col];
#pragma unroll
    for (int r = 0; r < 16; r++) {
        int rl = (r & 3) + 8 * (r >> 2) + 4 * (lane >> 5);
        int grow = M0 + rl;
        if (grow < M) {
            U[(size_t)grow * 128 + col] = (_Float16)(au[r] + bA);
            V[(size_t)grow * 128 + col] = (_Float16)av[r];
        }
    }
}

// ---------------------------------------------------------------------------
// GCN aggregation, slice-major + XCD-pinned (R4: FETCH 108->24MB, confirmed
// L2-resident) — but R4 went VALU-bound (67% VALUBusy, 176 lane-ops/edge vs
// 128 useful). R5: cut overhead — 4 lanes x 16B per row (4x fewer index/addr
// ops and vmem issues), byte-offset sidx (addr = 1 add), NO predication
// (tails cheaper than masks when VALU-bound; R2 proved tails latency-OK).
// DO NOT fuse into GEMM (R7 lesson: grid collapse kills gather parallelism).
// ---------------------------------------------------------------------------
__global__ __launch_bounds__(256, 6) void aggregate_kernel(const _Float16* __restrict__ y,
                                                           const float* __restrict__ dinv,
                                                           const int* __restrict__ ptr,
                                                           const int* __restrict__ ce_src,
                                                           const float* __restrict__ bias,
                                                           _Float16* __restrict__ out) {
    __shared__ int sidx[AECAP];     // byte offsets (src_node << 6)
    __shared__ int sptr[65];
    int b = blockIdx.x;
    int sl = (b & 7) >> 1;                     // slice 0..3 -> XCD pair
    int o = ((b >> 3) << 1) + (b & 1);         // node-group ordinal, 0..781
    int node0 = o * 64;
    int tid = threadIdx.x;
    if (tid < 65) {
        int nn = node0 + tid;
        sptr[tid] = ptr[nn < N_NODES ? nn : N_NODES];
    }
    __syncthreads();
    int base = sptr[0];
    int tot = sptr[64] - base;
    bool fit = (tot <= AECAP);
    if (fit) {
        for (int i = tid; i < tot; i += 256) sidx[i] = ce_src[base + i] << 6;
    }
    __syncthreads();

    int g = tid >> 2;                          // 64 node-groups per block
    int l = tid & 3;                           // 4 lanes x 16B = 64B row-slice
    int nodeIdx = node0 + g;
    int node = nodeIdx < N_NODES ? nodeIdx : N_NODES - 1;
    float di = dinv[node];
    const char* ysl = (const char*)y + (size_t)sl * (N_NODES * 64) + (size_t)l * 16;
    halfx8 self = *(const halfx8*)(ysl + (size_t)node * 64);
    float a0 = (float)self[0], a1 = (float)self[1], a2 = (float)self[2], a3 = (float)self[3];
    float a4 = (float)self[4], a5 = (float)self[5], a6 = (float)self[6], a7 = (float)self[7];
    int s0 = sptr[g], s1 = sptr[g + 1];

    if (fit) {
        int j = s0 - base, e = s1 - base;
        for (; j + 7 < e; j += 8) {
            halfx8 v0 = *(const halfx8*)(ysl + sidx[j]);
            halfx8 v1 = *(const halfx8*)(ysl + sidx[j + 1]);
            halfx8 v2 = *(const halfx8*)(ysl + sidx[j + 2]);
            halfx8 v3 = *(const halfx8*)(ysl + sidx[j + 3]);
            halfx8 v4 = *(const halfx8*)(ysl + sidx[j + 4]);
            halfx8 v5 = *(const halfx8*)(ysl + sidx[j + 5]);
            halfx8 v6 = *(const halfx8*)(ysl + sidx[j + 6]);
            halfx8 v7 = *(const halfx8*)(ysl + sidx[j + 7]);
            __builtin_amdgcn_sched_barrier(0);   // keep 8 gathers in flight
            a0 += (float)v0[0] + (float)v1[0] + (float)v2[0] + (float)v3[0]
                + (float)v4[0] + (float)v5[0] + (float)v6[0] + (float)v7[0];
            a1 += (float)v0[1] + (float)v1[1] + (float)v2[1] + (float)v3[1]
                + (float)v4[1] + (float)v5[1] + (float)v6[1] + (float)v7[1];
            a2 += (float)v0[2] + (float)v1[2] + (float)v2[2] + (float)v3[2]
                + (float)v4[2] + (float)v5[2] + (float)v6[2] + (float)v7[2];
            a3 += (float)v0[3] + (float)v1[3] + (float)v2[3] + (float)v3[3]
                + (float)v4[3] + (float)v5[3] + (float)v6[3] + (float)v7[3];
            a4 += (float)v0[4] + (float)v1[4] + (float)v2[4] + (float)v3[4]
                + (float)v4[4] + (float)v5[4] + (float)v6[4] + (float)v7[4];
            a5 += (float)v0[5] + (float)v1[5] + (float)v2[5] + (float)v3[5]
                + (float)v4[5] + (float)v5[5] + (float)v6[5] + (float)v7[5];
            a6 += (float)v0[6] + (float)v1[6] + (float)v2[6] + (float)v3[6]
                + (float)v4[6] + (float)v5[6] + (float)v6[6] + (float)v7[6];
            a7 += (float)v0[7] + (float)v1[7] + (float)v2[7] + (float)v3[7]
                + (float)v4[7] + (float)v5[7] + (float)v6[7] + (float)v7[7];
        }
        for (; j + 3 < e; j += 4) {
            halfx8 v0 = *(const halfx8*)(ysl + sidx[j]);
            halfx8 v1 = *(const halfx8*)(ysl + sidx[j + 1]);
            halfx8 v2 = *(const halfx8*)(ysl + sidx[j + 2]);
            halfx8 v3 = *(const halfx8*)(ysl + sidx[j + 3]);
            __builtin_amdgcn_sched_barrier(0);
            a0 += (float)v0[0] + (float)v1[0] + (float)v2[0] + (float)v3[0];
            a1 += (float)v0[1] + (float)v1[1] + (float)v2[1] + (float)v3[1];
            a2 += (float)v0[2] + (float)v1[2] + (float)v2[2] + (float)v3[2];
            a3 += (float)v0[3] + (float)v1[3] + (float)v2[3] + (float)v3[3];
            a4 += (float)v0[4] + (float)v1[4] + (float)v2[4] + (float)v3[4];
            a5 += (float)v0[5] + (float)v1[5] + (float)v2[5] + (float)v3[5];
            a6 += (float)v0[6] + (float)v1[6] + (float)v2[6] + (float)v3[6];
            a7 += (float)v0[7] + (float)v1[7] + (float)v2[7] + (float)v3[7];
        }
        for (; j < e; j++) {
            halfx8 v = *(const halfx8*)(ysl + sidx[j]);
            a0 += (float)v[0]; a1 += (float)v[1]; a2 += (float)v[2]; a3 += (float)v[3];
            a4 += (float)v[4]; a5 += (float)v[5]; a6 += (float)v[6]; a7 += (float)v[7];
        }
    } else {
        // cap-overflow fallback (P~0, kept for correctness)
        for (int j = s0; j < s1; j++) {
            halfx8 v = *(const halfx8*)(ysl + ((size_t)ce_src[j] << 6));
            a0 += (float)v[0]; a1 += (float)v[1]; a2 += (float)v[2]; a3 += (float)v[3];
            a4 += (float)v[4]; a5 += (float)v[5]; a6 += (float)v[6]; a7 += (float)v[7];
        }
    }
    if (nodeIdx < N_NODES) {
        const float* bp = &bias[sl * 32 + l * 8];
        float4 bv0 = *(const float4*)bp;
        float4 bv1 = *(const float4*)(bp + 4);
        halfx8 ov;
        ov[0] = (_Float16)fmaxf(di * a0 + bv0.x, 0.f);
        ov[1] = (_Float16)fmaxf(di * a1 + bv0.y, 0.f);
        ov[2] = (_Float16)fmaxf(di * a2 + bv0.z, 0.f);
        ov[3] = (_Float16)fmaxf(di * a3 + bv0.w, 0.f);
        ov[4] = (_Float16)fmaxf(di * a4 + bv1.x, 0.f);
        ov[5] = (_Float16)fmaxf(di * a5 + bv1.y, 0.f);
        ov[6] = (_Float16)fmaxf(di * a6 + bv1.z, 0.f);
        ov[7] = (_Float16)fmaxf(di * a7 + bv1.w, 0.f);
        *(halfx8*)&out[((size_t)sl * N_NODES + nodeIdx) * 32 + l * 8] = ov;
    }
}

// ---------------------------------------------------------------------------
// Edge MLP: 128 edges/block, 8 edges per 16-lane group (16 gathers in
// flight/thread — pinned with sched_barrier), packed fp16 add+relu +
// v_dot2_f32_f16 accumulation.
// ---------------------------------------------------------------------------
__global__ __launch_bounds__(256) void edge_mlp_kernel(const _Float16* __restrict__ Ub,
                                                       const _Float16* __restrict__ Vb,
                                                       const int* __restrict__ ce_src,
                                                       const int* __restrict__ ce_eid,
                                                       const int* __restrict__ ce_dst,
                                                       const _Float16* __restrict__ Wm2h,
                                                       const float* __restrict__ bm2,
                                                       float* __restrict__ out) {
    __shared__ int ssrc[128], sdst[128], seid[128];
    int tid = threadIdx.x;
    int e0 = blockIdx.x * 128;
    if (tid < 128) {
        ssrc[tid] = ce_src[e0 + tid];
        seid[tid] = ce_eid[e0 + tid];
    } else {
        sdst[tid - 128] = ce_dst[e0 + tid - 128];
    }
    __syncthreads();
    int g = tid >> 4;     // group 0..15
    int l = tid & 15;     // cols l*8 .. l*8+7
    halfx8 wv = *(const halfx8*)&Wm2h[l * 8];
    half2v w0 = {wv[0], wv[1]}, w1 = {wv[2], wv[3]}, w2 = {wv[4], wv[5]}, w3 = {wv[6], wv[7]};
    halfx8 uu[8], vv[8];
#pragma unroll
    for (int k = 0; k < 8; k++) {
        int e = g + 16 * k;
        uu[k] = *(const halfx8*)&Ub[(size_t)ssrc[e] * 128 + l * 8];
        vv[k] = *(const halfx8*)&Vb[(size_t)sdst[e] * 128 + l * 8];
    }
    __builtin_amdgcn_sched_barrier(0);   // keep all 16 gathers in flight
    float p[8];
#pragma unroll
    for (int k = 0; k < 8; k++) {
        halfx8 s = relu8(uu[k] + vv[k]);
        half2v s0 = {s[0], s[1]}, s1 = {s[2], s[3]}, s2 = {s[4], s[5]}, s3 = {s[6], s[7]};
        float acc = dot2acc(s0, w0, 0.f);
        acc = dot2acc(s1, w1, acc);
        acc = dot2acc(s2, w2, acc);
        p[k] = dot2acc(s3, w3, acc);
    }
#pragma unroll
    for (int d = 1; d < 16; d <<= 1) {
#pragma unroll
        for (int k = 0; k < 8; k++) p[k] += __shfl_xor(p[k], d);
    }
    if (l == 0) {
        float bb = bm2[0];
#pragma unroll
        for (int k = 0; k < 8; k++) out[seid[g + 16 * k]] = p[k] + bb;
    }
}

// ---------------------------------------------------------------------------
extern "C" void kernel_launch(void* const* d_in, const int* in_sizes, int n_in,
                              void* d_out, int out_size, void* d_ws, size_t ws_size,
                              hipStream_t stream) {
    const float* x    = (const float*)d_in[0];
    const int* eidx   = (const int*)d_in[1];
    const float* W_in = (const float*)d_in[2];
    const float* b_in = (const float*)d_in[3];
    const float* W1   = (const float*)d_in[4];
    const float* b1   = (const float*)d_in[5];
    const float* W2   = (const float*)d_in[6];
    const float* b2   = (const float*)d_in[7];
    const float* Wm1  = (const float*)d_in[8];
    const float* bm1  = (const float*)d_in[9];
    const float* Wm2  = (const float*)d_in[10];
    const float* bm2  = (const float*)d_in[11];
    float* out = (float*)d_out;
    const int* src = eidx;
    const int* dst = eidx + N_EDGES;

    char* w = (char*)d_ws;
    size_t off = 0;
    auto alloc = [&](size_t bytes) -> char* {
        char* p = w + off;
        off = (off + bytes + 255) & ~(size_t)255;
        return p;
    };
    int* bhist    = (int*)alloc((size_t)NB * 4);
    int* boff     = (int*)alloc((size_t)(NB + 1) * 4);
    int* bcursor  = (int*)alloc((size_t)NB * 4);
    int* csr_ptr  = (int*)alloc((size_t)(N_NODES + 1) * 4);
    float* dinv   = (float*)alloc((size_t)N_NODES * 4);
    unsigned long long* binned = (unsigned long long*)alloc((size_t)N_EDGES * 8);
    int* ce_src   = (int*)alloc((size_t)N_EDGES * 4);
    int* ce_eid   = (int*)alloc((size_t)N_EDGES * 4);
    int* ce_dst   = (int*)alloc((size_t)N_EDGES * 4);
    _Float16* Wp  = (_Float16*)alloc((size_t)77952 * 2);
    _Float16* y1  = (_Float16*)alloc((size_t)N_NODES * HID * 2);
    _Float16* y2  = (_Float16*)alloc((size_t)N_NODES * HID * 2);
    _Float16* hbuf = (_Float16*)alloc((size_t)N_NODES * HID * 2);
    _Float16* Ub  = (_Float16*)alloc((size_t)N_NODES * HID * 2);
    _Float16* Vb  = (_Float16*)alloc((size_t)N_NODES * HID * 2);

    const _Float16* WpIn  = Wp;              // K=96, steps 6
    const _Float16* Wp1   = Wp + 12288;      // K=128
    const _Float16* Wp2   = Wp + 28672;
    const _Float16* WpM1a = Wp + 45056;
    const _Float16* WpM1b = Wp + 61440;
    const _Float16* Wm2h  = Wp + 77824;

    // CSR build (counting sort) + weight pack (merged into pass 1)
    hipMemsetAsync(bhist, 0, (size_t)NB * 4, stream);
    hist_pack_kernel<<<196 + 305, 256, 0, stream>>>(dst, bhist, W_in, W1, W2, Wm1, Wm2, Wp);
    scan_buckets_kernel<<<1, 512, 0, stream>>>(bhist, boff, bcursor);
    bin_kernel<<<98, 512, 0, stream>>>(src, dst, bcursor, binned);
    bucket_sort_kernel<<<NB, 256, 0, stream>>>(binned, boff, ce_src, ce_eid, ce_dst,
                                               csr_ptr, dinv);

    int gblocks = (N_NODES + 31) / 32;  // 1563
    int ablocks = 782 * 4;              // 4 slices x 782 node-groups (64 nodes each)
    // y1 = (relu(x@W_in+b_in) @ W1) * dinv          (slice-major)
    fused_in_kernel<<<gblocks, 256, 0, stream>>>(x, WpIn, Wp1, b_in, dinv, y1, N_NODES);
    // h1 = relu(dinv*(y1_self + sum y1[src]) + b1)  -> hbuf (slice-major)
    aggregate_kernel<<<ablocks, 256, 0, stream>>>(y1, dinv, csr_ptr, ce_src, b1, hbuf);
    // y2 = (h1 @ W2) * dinv                         -> y2 (slice-major)
    gemm_f16_kernel<<<gblocks, 256, 0, stream>>>(hbuf, Wp2, nullptr, dinv, y2,
                                                 N_NODES, 8, 0);
    // h2 = relu(dinv*(y2_self + sum y2[src]) + b2)  -> hbuf (slice-major)
    aggregate_kernel<<<ablocks, 256, 0, stream>>>(y2, dinv, csr_ptr, ce_src, b2, hbuf);
    // U = h2@Wm1a+bm1, V = h2@Wm1b                  -> Ub, Vb (node-major)
    gemm_uv_kernel<<<gblocks, 256, 0, stream>>>(hbuf, WpM1a, WpM1b, bm1, Ub, Vb, N_NODES);
    // logits (CSR order, scatter by original edge id)
    edge_mlp_kernel<<<N_EDGES / 128, 256, 0, stream>>>(Ub, Vb, ce_src, ce_eid, ce_dst,
                                                       Wm2h, bm2, out);
}